// Round 7
// baseline (1436.344 us; speedup 1.0000x reference)
//
#include <hip/hip_runtime.h>
#include <hip/hip_cooperative_groups.h>

namespace cg = cooperative_groups;

#define D 128
#define WTS 132  // padded LDS row stride for gemm staging

// ---------- helpers ----------

__device__ __forceinline__ unsigned int encf(float f) {
  unsigned int u = __float_as_uint(f);
  return (u & 0x80000000u) ? ~u : (u | 0x80000000u);
}
__device__ __forceinline__ float decf(unsigned int e) {
  return __uint_as_float((e & 0x80000000u) ? (e & 0x7FFFFFFFu) : ~e);
}
__device__ __forceinline__ unsigned short f2bf(float f) {
  unsigned int u = __float_as_uint(f);
  u += 0x7FFFu + ((u >> 16) & 1u);  // rne
  return (unsigned short)(u >> 16);
}
__device__ __forceinline__ float bf_lo(unsigned int u) {
  return __uint_as_float(u << 16);
}
__device__ __forceinline__ float bf_hi(unsigned int u) {
  return __uint_as_float(u & 0xFFFF0000u);
}

// JAX threefry2x32 (20 rounds), exact.
__device__ __forceinline__ void tf2x32(unsigned int k0, unsigned int k1,
                                       unsigned int& x0, unsigned int& x1) {
  unsigned int ks[3] = {k0, k1, k0 ^ k1 ^ 0x1BD11BDAu};
  x0 += ks[0]; x1 += ks[1];
  const unsigned int rotA[4] = {13u, 15u, 26u, 6u};
  const unsigned int rotB[4] = {17u, 29u, 16u, 24u};
#pragma unroll
  for (int g = 0; g < 5; ++g) {
    const unsigned int* rot = (g & 1) ? rotB : rotA;
#pragma unroll
    for (int i = 0; i < 4; ++i) {
      x0 += x1;
      x1 = (x1 << rot[i]) | (x1 >> (32u - rot[i]));
      x1 ^= x0;
    }
    x0 += ks[(g + 1) % 3];
    x1 += ks[(g + 2) % 3] + (unsigned int)(g + 1);
  }
}

// ---------- node 1: both GEMMs, one dispatch ----------
// Y = X @ W^T (fp32 VALU, D=128). Slabs 0..slabs_s-1 -> state/W_l -> xl+xlh;
// rest -> model/W_r -> xrh only.

__global__ __launch_bounds__(256) void gemm_both(
    const float* __restrict__ Xs, const float* __restrict__ Xm,
    const float* __restrict__ Wl, const float* __restrict__ Wr,
    float* __restrict__ Yxl, unsigned short* __restrict__ Yxlh,
    unsigned short* __restrict__ Yxrh, int ns, int nm) {
  __shared__ float WT[64 * WTS];  // WT[k'][c]
  int tid = threadIdx.x;
  int q = tid & 15;
  int rg = tid >> 4;
  int slabs_s = (ns + 127) >> 7;
  int slabs_m = (nm + 127) >> 7;

  for (int sl = blockIdx.x; sl < slabs_s + slabs_m; sl += gridDim.x) {
    const float* X; const float* W; float* Yf; unsigned short* Yh; int N;
    long long r0;
    if (sl < slabs_s) {
      X = Xs; W = Wl; Yf = Yxl; Yh = Yxlh; N = ns;
      r0 = (long long)sl * 128;
    } else {
      X = Xm; W = Wr; Yf = nullptr; Yh = Yxrh; N = nm;
      r0 = (long long)(sl - slabs_s) * 128;
    }

    float acc[8][8];
#pragma unroll
    for (int r = 0; r < 8; ++r)
#pragma unroll
      for (int c = 0; c < 8; ++c) acc[r][c] = 0.f;

    long long rbase = r0 + (long long)rg * 8;

#pragma unroll
    for (int phase = 0; phase < 2; ++phase) {
      const int kbase = phase * 64;
      __syncthreads();
      for (int i = tid; i < 2048; i += 256) {
        int c = i >> 4;
        int j = i & 15;
        float4 w4 = *(const float4*)(W + c * D + kbase + 4 * j);
        WT[(4 * j + 0) * WTS + c] = w4.x;
        WT[(4 * j + 1) * WTS + c] = w4.y;
        WT[(4 * j + 2) * WTS + c] = w4.z;
        WT[(4 * j + 3) * WTS + c] = w4.w;
      }
      __syncthreads();

      for (int k4 = 0; k4 < 64; k4 += 4) {
        float4 xr_[8];
#pragma unroll
        for (int r = 0; r < 8; ++r) {
          long long rr = rbase + r;
          if (rr >= N) rr = N - 1;
          xr_[r] = *(const float4*)(X + rr * D + kbase + k4);
        }
#pragma unroll
        for (int kk = 0; kk < 4; ++kk) {
          float4 wa = *(const float4*)(WT + (k4 + kk) * WTS + 4 * q);
          float4 wb = *(const float4*)(WT + (k4 + kk) * WTS + 64 + 4 * q);
#pragma unroll
          for (int r = 0; r < 8; ++r) {
            float xv = (&xr_[r].x)[kk];
            acc[r][0] += xv * wa.x; acc[r][1] += xv * wa.y;
            acc[r][2] += xv * wa.z; acc[r][3] += xv * wa.w;
            acc[r][4] += xv * wb.x; acc[r][5] += xv * wb.y;
            acc[r][6] += xv * wb.z; acc[r][7] += xv * wb.w;
          }
        }
      }
    }

#pragma unroll
    for (int r = 0; r < 8; ++r) {
      long long rr = rbase + r;
      if (rr < N) {
        if (Yf) {
          float* yp = Yf + rr * D;
          *(float4*)(yp + 4 * q) =
              make_float4(acc[r][0], acc[r][1], acc[r][2], acc[r][3]);
          *(float4*)(yp + 64 + 4 * q) =
              make_float4(acc[r][4], acc[r][5], acc[r][6], acc[r][7]);
        }
        unsigned short* hp = Yh + rr * D;
        uint2 pa, pb;
        pa.x = (unsigned int)f2bf(acc[r][0]) | ((unsigned int)f2bf(acc[r][1]) << 16);
        pa.y = (unsigned int)f2bf(acc[r][2]) | ((unsigned int)f2bf(acc[r][3]) << 16);
        pb.x = (unsigned int)f2bf(acc[r][4]) | ((unsigned int)f2bf(acc[r][5]) << 16);
        pb.y = (unsigned int)f2bf(acc[r][6]) | ((unsigned int)f2bf(acc[r][7]) << 16);
        *(uint2*)(hp + 4 * q) = pa;
        *(uint2*)(hp + 64 + 4 * q) = pb;
      }
    }
  }
}

// ---------- node 2: cooperative GAT (zero+norm / scores / expsum / coef / wsum) --

__global__ __launch_bounds__(256) void gat_coop(
    const int* __restrict__ ei, int* __restrict__ src32,
    int* __restrict__ dst32, const unsigned short* __restrict__ xlh,
    const unsigned short* __restrict__ xrh, const float* __restrict__ xl,
    const float* __restrict__ att, float* __restrict__ e_sc,
    unsigned int* __restrict__ m_enc, float* __restrict__ s_sum,
    float* __restrict__ coef, float* __restrict__ g_acc, int ne, int ns,
    int nm) {
  cg::grid_group grid = cg::this_grid();
  int tid = threadIdx.x;
  int gid = blockIdx.x * 256 + tid;
  int gstride = gridDim.x * 256;

  // ---- phase 0: zero accumulators + normalize edge index ----
  for (int i = gid; i < nm; i += gstride) { m_enc[i] = 0u; s_sum[i] = 0.f; }
  for (int i = gid; i < ns; i += gstride) coef[i] = 0.f;
  if (gid < D) g_acc[gid] = 0.f;
  __shared__ int is64;
  if (tid == 0) {
    int any = 0;
    for (int i = 1; i < 256; i += 2) any |= ei[i];
    is64 = (any == 0);
  }
  __syncthreads();
  int flag = is64;
  for (int i = gid; i < ne; i += gstride) {
    int s = flag ? ei[2 * i] : ei[i];
    int d = flag ? ei[2 * ne + 2 * i] : ei[ne + i];
    s = s < 0 ? 0 : (s >= ns ? ns - 1 : s);
    d = d < 0 ? 0 : (d >= nm ? nm - 1 : d);
    src32[i] = s;
    dst32[i] = d;
  }
  grid.sync();

  // ---- phase 1: edge scores + segment max (bf16 rows, quarter-wave/edge x2) ----
  {
    int lane = tid & 63;
    int q = lane & 15;
    int sub = lane >> 4;
    int wid = (blockIdx.x * 256 + tid) >> 6;
    int nw = (gridDim.x * 256) >> 6;
    float4 a0 = ((const float4*)att)[2 * q];
    float4 a1 = ((const float4*)att)[2 * q + 1];
    for (int e0 = wid * 8; e0 < ne; e0 += nw * 8) {
      int eA = e0 + sub, eB = e0 + 4 + sub;
      int okA = eA < ne, okB = eB < ne;
      int sA = okA ? src32[eA] : 0, dA = okA ? dst32[eA] : 0;
      int sB = okB ? src32[eB] : 0, dB = okB ? dst32[eB] : 0;
      uint4 lA = *(const uint4*)(xlh + (long long)sA * D + q * 8);
      uint4 rA = *(const uint4*)(xrh + (long long)dA * D + q * 8);
      uint4 lB = *(const uint4*)(xlh + (long long)sB * D + q * 8);
      uint4 rB = *(const uint4*)(xrh + (long long)dB * D + q * 8);
      float z, vA = 0.f, vB = 0.f;
      z = bf_lo(lA.x) + bf_lo(rA.x); vA += (z > 0.f ? z : 0.2f * z) * a0.x;
      z = bf_hi(lA.x) + bf_hi(rA.x); vA += (z > 0.f ? z : 0.2f * z) * a0.y;
      z = bf_lo(lA.y) + bf_lo(rA.y); vA += (z > 0.f ? z : 0.2f * z) * a0.z;
      z = bf_hi(lA.y) + bf_hi(rA.y); vA += (z > 0.f ? z : 0.2f * z) * a0.w;
      z = bf_lo(lA.z) + bf_lo(rA.z); vA += (z > 0.f ? z : 0.2f * z) * a1.x;
      z = bf_hi(lA.z) + bf_hi(rA.z); vA += (z > 0.f ? z : 0.2f * z) * a1.y;
      z = bf_lo(lA.w) + bf_lo(rA.w); vA += (z > 0.f ? z : 0.2f * z) * a1.z;
      z = bf_hi(lA.w) + bf_hi(rA.w); vA += (z > 0.f ? z : 0.2f * z) * a1.w;
      z = bf_lo(lB.x) + bf_lo(rB.x); vB += (z > 0.f ? z : 0.2f * z) * a0.x;
      z = bf_hi(lB.x) + bf_hi(rB.x); vB += (z > 0.f ? z : 0.2f * z) * a0.y;
      z = bf_lo(lB.y) + bf_lo(rB.y); vB += (z > 0.f ? z : 0.2f * z) * a0.z;
      z = bf_hi(lB.y) + bf_hi(rB.y); vB += (z > 0.f ? z : 0.2f * z) * a0.w;
      z = bf_lo(lB.z) + bf_lo(rB.z); vB += (z > 0.f ? z : 0.2f * z) * a1.x;
      z = bf_hi(lB.z) + bf_hi(rB.z); vB += (z > 0.f ? z : 0.2f * z) * a1.y;
      z = bf_lo(lB.w) + bf_lo(rB.w); vB += (z > 0.f ? z : 0.2f * z) * a1.z;
      z = bf_hi(lB.w) + bf_hi(rB.w); vB += (z > 0.f ? z : 0.2f * z) * a1.w;
#pragma unroll
      for (int o = 8; o > 0; o >>= 1) vA += __shfl_xor(vA, o, 64);
#pragma unroll
      for (int o = 8; o > 0; o >>= 1) vB += __shfl_xor(vB, o, 64);
      if (q == 0) {
        if (okA) { e_sc[eA] = vA; atomicMax(&m_enc[dA], encf(vA)); }
        if (okB) { e_sc[eB] = vB; atomicMax(&m_enc[dB], encf(vB)); }
      }
    }
  }
  grid.sync();

  // ---- phase 2: denominators ----
  for (int i = gid; i < ne; i += gstride) {
    int d_ = dst32[i];
    atomicAdd(&s_sum[d_], expf(e_sc[i] - decf(m_enc[d_])));
  }
  grid.sync();

  // ---- phase 3: per-source coefficients ----
  for (int i = gid; i < ne; i += gstride) {
    int d_ = dst32[i];
    float w = expf(e_sc[i] - decf(m_enc[d_])) / s_sum[d_];
    atomicAdd(&coef[src32[i]], w);
  }
  grid.sync();

  // ---- phase 4: g_acc[d] = sum_s coef[s] * xl[s][d] ----
  {
    __shared__ float red[4][D];
    int lane = tid & 63;
    int wv = tid >> 6;
    int wid = blockIdx.x * 4 + wv;
    int nw = gridDim.x * 4;
    float ax = 0.f, ay = 0.f;
    for (int s = wid; s < ns; s += nw) {
      float w = coef[s];
      float2 x2 = ((const float2*)(xl + (long long)s * D))[lane];
      ax += w * x2.x;
      ay += w * x2.y;
    }
    red[wv][2 * lane] = ax;
    red[wv][2 * lane + 1] = ay;
    __syncthreads();
    if (tid < D) {
      float t = red[0][tid] + red[1][tid] + red[2][tid] + red[3][tid];
      atomicAdd(&g_acc[tid], t);
    }
  }
}

// ---------- node 3: cooperative LSTM/sample chain (all 8 steps) ----------

__global__ __launch_bounds__(256) void chain_coop(
    const float* __restrict__ g_acc, const float* __restrict__ conv_bias,
    const float* __restrict__ Wih, const float* __restrict__ Whh,
    const float* __restrict__ bih, const float* __restrict__ bhh,
    const float* __restrict__ emb, const float* __restrict__ W1,
    const float* __restrict__ b1, const float* __restrict__ W2,
    const float* __restrict__ b2, float* __restrict__ st_hidden,
    unsigned int* __restrict__ cand_enc, int* __restrict__ cand_j,
    float* __restrict__ cand_lg, float* __restrict__ sumexp,
    float* __restrict__ out, int nm, float nmf) {
  cg::grid_group grid = cg::this_grid();
  __shared__ float sh_hid[D];
  __shared__ float sh_h[D], sh_c[D], sh_vin[D];
  __shared__ float sh_g[4 * D];
  __shared__ unsigned int s_enc[256];
  __shared__ int s_j[256];
  __shared__ float s_lg[256], s_ex[256];
  int tid = threadIdx.x;
  int bid = blockIdx.x;

  // ---- preamble (block 0): t=0 state ----
  if (bid == 0) {
    if (tid < 8) sumexp[tid] = 0.f;
    if (tid < D) sh_vin[tid] = g_acc[tid] / nmf + conv_bias[tid];
    __syncthreads();
    for (int r = tid; r < 4 * D; r += 256) {
      const float4* wi = (const float4*)(Wih + (long long)r * D);
      float s0 = 0.f, s1 = 0.f, s2 = 0.f, s3 = 0.f;
#pragma unroll 8
      for (int k = 0; k < 32; ++k) {
        float4 w = wi[k];
        s0 += w.x * sh_vin[4 * k];
        s1 += w.y * sh_vin[4 * k + 1];
        s2 += w.z * sh_vin[4 * k + 2];
        s3 += w.w * sh_vin[4 * k + 3];
      }
      sh_g[r] = ((s0 + s1) + (s2 + s3)) + bih[r] + bhh[r];  // h0 = 0
    }
    __syncthreads();
    if (tid < D) {
      float i_ = 1.f / (1.f + expf(-sh_g[tid]));
      float g_ = tanhf(sh_g[2 * D + tid]);
      float o_ = 1.f / (1.f + expf(-sh_g[3 * D + tid]));
      float cn = i_ * g_;  // f*c0 = 0
      float hn = o_ * tanhf(cn);
      sh_c[tid] = cn;
      sh_h[tid] = hn;
    }
    __syncthreads();
    if (tid < D) {
      const float4* w = (const float4*)(W1 + tid * D);
      float s0 = 0.f, s1 = 0.f, s2 = 0.f, s3 = 0.f;
#pragma unroll 8
      for (int k = 0; k < 32; ++k) {
        float4 ww = w[k];
        s0 += ww.x * sh_h[4 * k];
        s1 += ww.y * sh_h[4 * k + 1];
        s2 += ww.z * sh_h[4 * k + 2];
        s3 += ww.w * sh_h[4 * k + 3];
      }
      st_hidden[tid] = fmaxf(((s0 + s1) + (s2 + s3)) + b1[tid], 0.f);
    }
    __threadfence();
  }
  grid.sync();

  for (int t = 0; t < 8; ++t) {
    // ---- phase A (all blocks): logits + gumbel + block candidate ----
    if (tid < D) sh_hid[tid] = st_hidden[tid];
    __syncthreads();
    unsigned int k0, k1;
    {
      unsigned int x0 = 0u, x1 = (unsigned int)t;
      tf2x32(0u, 42u, x0, x1);
      k0 = x0; k1 = x1;
    }
    int j = bid * 256 + tid;
    unsigned int bestE = 0u;
    int bestJ = 0x7FFFFFFF;
    float bestL = 0.f, ex = 0.f;
    if (j < nm) {
      const float4* w = (const float4*)(W2 + (long long)j * D);
      float s0 = 0.f, s1 = 0.f, s2 = 0.f, s3 = 0.f;
#pragma unroll 8
      for (int k = 0; k < 32; ++k) {
        float4 ww = w[k];
        s0 += ww.x * sh_hid[4 * k];
        s1 += ww.y * sh_hid[4 * k + 1];
        s2 += ww.z * sh_hid[4 * k + 2];
        s3 += ww.w * sh_hid[4 * k + 3];
      }
      float lv = ((s0 + s1) + (s2 + s3)) + b2[j];
      ex = expf(lv);
      unsigned int x0 = 0u, x1 = (unsigned int)j;
      tf2x32(k0, k1, x0, x1);
      unsigned int bits = x0 ^ x1;
      float f = __uint_as_float((bits >> 9) | 0x3f800000u) - 1.0f;
      const float tiny = 1.1754943508222875e-38f;
      float u = fmaxf(tiny, f * (1.0f - tiny) + tiny);
      float pert = lv + (-logf(-logf(u)));
      bestE = encf(pert);
      bestJ = j;
      bestL = lv;
    }
    s_enc[tid] = bestE; s_j[tid] = bestJ; s_lg[tid] = bestL; s_ex[tid] = ex;
    __syncthreads();
    for (int s = 128; s > 0; s >>= 1) {
      if (tid < s) {
        s_ex[tid] += s_ex[tid + s];
        unsigned int eo = s_enc[tid + s];
        if (eo > s_enc[tid] || (eo == s_enc[tid] && s_j[tid + s] < s_j[tid])) {
          s_enc[tid] = eo; s_j[tid] = s_j[tid + s]; s_lg[tid] = s_lg[tid + s];
        }
      }
      __syncthreads();
    }
    if (tid == 0) {
      cand_enc[bid] = s_enc[0];
      cand_j[bid] = s_j[0];
      cand_lg[bid] = s_lg[0];
      atomicAdd(&sumexp[t], s_ex[0]);
      __threadfence();
    }
    grid.sync();

    // ---- phase B (block 0): global argmax + outputs + next state ----
    if (bid == 0) {
      int nb = (int)gridDim.x;
      s_enc[tid] = (tid < nb) ? cand_enc[tid] : 0u;
      s_j[tid] = (tid < nb) ? cand_j[tid] : 0x7FFFFFFF;
      s_lg[tid] = (tid < nb) ? cand_lg[tid] : 0.f;
      __syncthreads();
      for (int s = 128; s > 0; s >>= 1) {
        if (tid < s) {
          unsigned int eo = s_enc[tid + s];
          if (eo > s_enc[tid] || (eo == s_enc[tid] && s_j[tid + s] < s_j[tid])) {
            s_enc[tid] = eo; s_j[tid] = s_j[tid + s]; s_lg[tid] = s_lg[tid + s];
          }
        }
        __syncthreads();
      }
      int a = s_j[0];
      float lga = s_lg[0];
      if (a < 0 || a >= nm) a = 0;
      if (tid == 0) {
        float se = sumexp[t];
        out[t] = (float)a;
        out[8 + t] = lga - logf(se);
      }
      if (t < 7) {
        if (tid < D) sh_vin[tid] = emb[(long long)a * D + tid];
        __syncthreads();
        for (int r = tid; r < 4 * D; r += 256) {
          const float4* wi = (const float4*)(Wih + (long long)r * D);
          const float4* wh = (const float4*)(Whh + (long long)r * D);
          float s0 = 0.f, s1 = 0.f, s2 = 0.f, s3 = 0.f;
#pragma unroll 8
          for (int k = 0; k < 32; ++k) {
            float4 wa = wi[k], wb = wh[k];
            s0 += wa.x * sh_vin[4 * k] + wb.x * sh_h[4 * k];
            s1 += wa.y * sh_vin[4 * k + 1] + wb.y * sh_h[4 * k + 1];
            s2 += wa.z * sh_vin[4 * k + 2] + wb.z * sh_h[4 * k + 2];
            s3 += wa.w * sh_vin[4 * k + 3] + wb.w * sh_h[4 * k + 3];
          }
          sh_g[r] = ((s0 + s1) + (s2 + s3)) + bih[r] + bhh[r];
        }
        __syncthreads();
        if (tid < D) {
          float i_ = 1.f / (1.f + expf(-sh_g[tid]));
          float f_ = 1.f / (1.f + expf(-sh_g[D + tid]));
          float g_ = tanhf(sh_g[2 * D + tid]);
          float o_ = 1.f / (1.f + expf(-sh_g[3 * D + tid]));
          float cn = f_ * sh_c[tid] + i_ * g_;
          float hn = o_ * tanhf(cn);
          sh_c[tid] = cn;
          sh_h[tid] = hn;
        }
        __syncthreads();
        if (tid < D) {
          const float4* w = (const float4*)(W1 + tid * D);
          float s0 = 0.f, s1 = 0.f, s2 = 0.f, s3 = 0.f;
#pragma unroll 8
          for (int k = 0; k < 32; ++k) {
            float4 ww = w[k];
            s0 += ww.x * sh_h[4 * k];
            s1 += ww.y * sh_h[4 * k + 1];
            s2 += ww.z * sh_h[4 * k + 2];
            s3 += ww.w * sh_h[4 * k + 3];
          }
          st_hidden[tid] = fmaxf(((s0 + s1) + (s2 + s3)) + b1[tid], 0.f);
        }
        __threadfence();
      } else {
        if (tid < D) {
          out[16 + tid] = sh_h[tid];
          out[144 + tid] = sh_c[tid];
        }
      }
    }
    grid.sync();
  }
}

// ---------- launch ----------

extern "C" void kernel_launch(void* const* d_in, const int* in_sizes, int n_in,
                              void* d_out, int out_size, void* d_ws, size_t ws_size,
                              hipStream_t stream) {
  const float* state_features = (const float*)d_in[0];
  const float* model_features = (const float*)d_in[1];
  const int* edge_index = (const int*)d_in[2];
  const float* W_l = (const float*)d_in[3];
  const float* W_r = (const float*)d_in[4];
  const float* att = (const float*)d_in[5];
  const float* conv_bias = (const float*)d_in[6];
  const float* Wih = (const float*)d_in[7];
  const float* Whh = (const float*)d_in[8];
  const float* bih = (const float*)d_in[9];
  const float* bhh = (const float*)d_in[10];
  const float* W1 = (const float*)d_in[11];
  const float* b1 = (const float*)d_in[12];
  const float* W2 = (const float*)d_in[13];
  const float* b2 = (const float*)d_in[14];
  const float* emb = (const float*)d_in[15];
  float* out = (float*)d_out;

  int NS = in_sizes[0] / D;
  int NM = in_sizes[1] / D;
  int E = in_sizes[2] / 2;

  char* ws = (char*)d_ws;
  size_t off = 0;
  auto alloc = [&](size_t bytes) -> void* {
    void* p = ws + off;
    off = (off + bytes + 255) & ~(size_t)255;
    return p;
  };
  float* xl = (float*)alloc((size_t)NS * D * 4);
  unsigned short* xlh = (unsigned short*)alloc((size_t)NS * D * 2);
  unsigned short* xrh = (unsigned short*)alloc((size_t)NM * D * 2);
  float* e_sc = (float*)alloc((size_t)E * 4);
  int* src32 = (int*)alloc((size_t)E * 4);
  int* dst32 = (int*)alloc((size_t)E * 4);
  unsigned int* m_enc = (unsigned int*)alloc((size_t)NM * 4);
  float* s_sum = (float*)alloc((size_t)NM * 4);
  float* coef = (float*)alloc((size_t)NS * 4);
  float* g_acc = (float*)alloc(D * 4);
  float* st_hidden = (float*)alloc(D * 4);
  float* st_sumexp = (float*)alloc(8 * 4);
  unsigned int* cand_enc = (unsigned int*)alloc(256 * 4);
  int* cand_j = (int*)alloc(256 * 4);
  float* cand_lg = (float*)alloc(256 * 4);

  // node 1: both gemms
  int slabs = (NS + 127) / 128 + (NM + 127) / 128;
  gemm_both<<<slabs, 256, 0, stream>>>(state_features, model_features, W_l, W_r,
                                       xl, xlh, xrh, NS, NM);

  // node 2: cooperative GAT
  {
    void* args[] = {(void*)&edge_index, (void*)&src32, (void*)&dst32,
                    (void*)&xlh,        (void*)&xrh,   (void*)&xl,
                    (void*)&att,        (void*)&e_sc,  (void*)&m_enc,
                    (void*)&s_sum,      (void*)&coef,  (void*)&g_acc,
                    (void*)&E,          (void*)&NS,    (void*)&NM};
    hipLaunchCooperativeKernel((void*)gat_coop, dim3(1024), dim3(256), args, 0,
                               stream);
  }

  // node 3: cooperative chain
  {
    float nmf = (float)NM;
    int NB = (NM + 255) / 256;  // 196
    void* args[] = {(void*)&g_acc,    (void*)&conv_bias, (void*)&Wih,
                    (void*)&Whh,      (void*)&bih,       (void*)&bhh,
                    (void*)&emb,      (void*)&W1,        (void*)&b1,
                    (void*)&W2,       (void*)&b2,        (void*)&st_hidden,
                    (void*)&cand_enc, (void*)&cand_j,    (void*)&cand_lg,
                    (void*)&st_sumexp, (void*)&out,      (void*)&NM,
                    (void*)&nmf};
    hipLaunchCooperativeKernel((void*)chain_coop, dim3((NM + 255) / 256),
                               dim3(256), args, 0, stream);
    (void)NB;
  }
}

// Round 8
// 675.936 us; speedup vs baseline: 2.1250x; 2.1250x over previous
//
#include <hip/hip_runtime.h>

#define D 128
#define WTS 132  // padded LDS row stride for gemm staging

// ---------- helpers ----------

__device__ __forceinline__ unsigned int encf(float f) {
  unsigned int u = __float_as_uint(f);
  return (u & 0x80000000u) ? ~u : (u | 0x80000000u);
}
__device__ __forceinline__ float decf(unsigned int e) {
  return __uint_as_float((e & 0x80000000u) ? (e & 0x7FFFFFFFu) : ~e);
}
__device__ __forceinline__ unsigned short f2bf(float f) {
  unsigned int u = __float_as_uint(f);
  u += 0x7FFFu + ((u >> 16) & 1u);  // rne
  return (unsigned short)(u >> 16);
}
__device__ __forceinline__ float bf_lo(unsigned int u) {
  return __uint_as_float(u << 16);
}
__device__ __forceinline__ float bf_hi(unsigned int u) {
  return __uint_as_float(u & 0xFFFF0000u);
}

// JAX threefry2x32 (20 rounds), exact.
__device__ __forceinline__ void tf2x32(unsigned int k0, unsigned int k1,
                                       unsigned int& x0, unsigned int& x1) {
  unsigned int ks[3] = {k0, k1, k0 ^ k1 ^ 0x1BD11BDAu};
  x0 += ks[0]; x1 += ks[1];
  const unsigned int rotA[4] = {13u, 15u, 26u, 6u};
  const unsigned int rotB[4] = {17u, 29u, 16u, 24u};
#pragma unroll
  for (int g = 0; g < 5; ++g) {
    const unsigned int* rot = (g & 1) ? rotB : rotA;
#pragma unroll
    for (int i = 0; i < 4; ++i) {
      x0 += x1;
      x1 = (x1 << rot[i]) | (x1 >> (32u - rot[i]));
      x1 ^= x0;
    }
    x0 += ks[(g + 1) % 3];
    x1 += ks[(g + 2) % 3] + (unsigned int)(g + 1);
  }
}

// ---------- node 1: prologue (zero + edge-normalize) + both GEMMs ----------
// Y = X @ W^T (fp32 VALU, D=128), outputs bf16 rows only.

__global__ __launch_bounds__(256) void gemm_pro(
    const float* __restrict__ Xs, const float* __restrict__ Xm,
    const float* __restrict__ Wl, const float* __restrict__ Wr,
    unsigned short* __restrict__ Yxlh, unsigned short* __restrict__ Yxrh,
    const int* __restrict__ ei, int* __restrict__ src32,
    int* __restrict__ dst32, unsigned int* __restrict__ m_enc,
    float* __restrict__ s_sum, float* __restrict__ coef,
    float* __restrict__ g_acc, unsigned long long* __restrict__ amax,
    float* __restrict__ sumexp, int ne, int ns, int nm) {
  int tid = threadIdx.x;
  int gid = blockIdx.x * 256 + tid;
  int gstride = gridDim.x * 256;

  // ---- prologue: zero accumulators ----
  for (int i = gid; i < nm; i += gstride) { m_enc[i] = 0u; s_sum[i] = 0.f; }
  for (int i = gid; i < ns; i += gstride) coef[i] = 0.f;
  if (gid < D) g_acc[gid] = 0.f;
  if (gid < 8) { amax[gid] = 0ull; sumexp[gid] = 0.f; }
  // ---- prologue: edge index normalization (int32 vs int64 runtime detect) ----
  __shared__ int is64;
  if (tid == 0) {
    int any = 0;
    for (int i = 1; i < 256; i += 2) any |= ei[i];
    is64 = (any == 0);
  }
  __syncthreads();
  int flag = is64;
  for (int i = gid; i < ne; i += gstride) {
    int s = flag ? ei[2 * i] : ei[i];
    int d = flag ? ei[2 * ne + 2 * i] : ei[ne + i];
    s = s < 0 ? 0 : (s >= ns ? ns - 1 : s);
    d = d < 0 ? 0 : (d >= nm ? nm - 1 : d);
    src32[i] = s;
    dst32[i] = d;
  }

  // ---- both GEMMs via slab loop ----
  __shared__ float WT[64 * WTS];  // WT[k'][c]
  int q = tid & 15;
  int rg = tid >> 4;
  int slabs_s = (ns + 127) >> 7;
  int slabs_m = (nm + 127) >> 7;

  for (int sl = blockIdx.x; sl < slabs_s + slabs_m; sl += gridDim.x) {
    const float* X; const float* W; unsigned short* Yh; int N;
    long long r0;
    if (sl < slabs_s) {
      X = Xs; W = Wl; Yh = Yxlh; N = ns;
      r0 = (long long)sl * 128;
    } else {
      X = Xm; W = Wr; Yh = Yxrh; N = nm;
      r0 = (long long)(sl - slabs_s) * 128;
    }

    float acc[8][8];
#pragma unroll
    for (int r = 0; r < 8; ++r)
#pragma unroll
      for (int c = 0; c < 8; ++c) acc[r][c] = 0.f;

    // clamp once per slab: tail rg-groups recompute last rows (benign
    // identical duplicate writes) so the k-loop has no per-load clamp.
    long long rbase = r0 + (long long)rg * 8;
    if (rbase > (long long)N - 8) rbase = (long long)N - 8;

#pragma unroll
    for (int phase = 0; phase < 2; ++phase) {
      const int kbase = phase * 64;
      __syncthreads();
      for (int i = tid; i < 2048; i += 256) {
        int c = i >> 4;
        int j = i & 15;
        float4 w4 = *(const float4*)(W + c * D + kbase + 4 * j);
        WT[(4 * j + 0) * WTS + c] = w4.x;
        WT[(4 * j + 1) * WTS + c] = w4.y;
        WT[(4 * j + 2) * WTS + c] = w4.z;
        WT[(4 * j + 3) * WTS + c] = w4.w;
      }
      __syncthreads();

      for (int k4 = 0; k4 < 64; k4 += 4) {
        float4 xr_[8];
#pragma unroll
        for (int r = 0; r < 8; ++r)
          xr_[r] = *(const float4*)(X + (rbase + r) * D + kbase + k4);
#pragma unroll
        for (int kk = 0; kk < 4; ++kk) {
          float4 wa = *(const float4*)(WT + (k4 + kk) * WTS + 4 * q);
          float4 wb = *(const float4*)(WT + (k4 + kk) * WTS + 64 + 4 * q);
#pragma unroll
          for (int r = 0; r < 8; ++r) {
            float xv = (&xr_[r].x)[kk];
            acc[r][0] += xv * wa.x; acc[r][1] += xv * wa.y;
            acc[r][2] += xv * wa.z; acc[r][3] += xv * wa.w;
            acc[r][4] += xv * wb.x; acc[r][5] += xv * wb.y;
            acc[r][6] += xv * wb.z; acc[r][7] += xv * wb.w;
          }
        }
      }
    }

#pragma unroll
    for (int r = 0; r < 8; ++r) {
      unsigned short* hp = Yh + (rbase + r) * D;
      uint2 pa, pb;
      pa.x = (unsigned int)f2bf(acc[r][0]) | ((unsigned int)f2bf(acc[r][1]) << 16);
      pa.y = (unsigned int)f2bf(acc[r][2]) | ((unsigned int)f2bf(acc[r][3]) << 16);
      pb.x = (unsigned int)f2bf(acc[r][4]) | ((unsigned int)f2bf(acc[r][5]) << 16);
      pb.y = (unsigned int)f2bf(acc[r][6]) | ((unsigned int)f2bf(acc[r][7]) << 16);
      *(uint2*)(hp + 4 * q) = pa;
      *(uint2*)(hp + 64 + 4 * q) = pb;
    }
  }
}

// ---------- edge pass 1: scores + segment max (bf16 rows, quarter-wave/edge x2) --

__global__ __launch_bounds__(256) void edge_scores(
    const unsigned short* __restrict__ xlh, const unsigned short* __restrict__ xrh,
    const int* __restrict__ src, const int* __restrict__ dst,
    const float* __restrict__ att, float* __restrict__ e_sc,
    unsigned int* __restrict__ m_enc, int ne) {
  int tid = threadIdx.x;
  int lane = tid & 63;
  int q = lane & 15;
  int sub = lane >> 4;
  int wid = (blockIdx.x * 256 + tid) >> 6;
  int nw = (gridDim.x * 256) >> 6;
  float4 a0 = ((const float4*)att)[2 * q];
  float4 a1 = ((const float4*)att)[2 * q + 1];
  for (int e0 = wid * 8; e0 < ne; e0 += nw * 8) {
    int eA = e0 + sub, eB = e0 + 4 + sub;
    int okA = eA < ne, okB = eB < ne;
    int sA = okA ? src[eA] : 0, dA = okA ? dst[eA] : 0;
    int sB = okB ? src[eB] : 0, dB = okB ? dst[eB] : 0;
    uint4 lA = *(const uint4*)(xlh + (long long)sA * D + q * 8);
    uint4 rA = *(const uint4*)(xrh + (long long)dA * D + q * 8);
    uint4 lB = *(const uint4*)(xlh + (long long)sB * D + q * 8);
    uint4 rB = *(const uint4*)(xrh + (long long)dB * D + q * 8);
    float z, vA = 0.f, vB = 0.f;
    z = bf_lo(lA.x) + bf_lo(rA.x); vA += (z > 0.f ? z : 0.2f * z) * a0.x;
    z = bf_hi(lA.x) + bf_hi(rA.x); vA += (z > 0.f ? z : 0.2f * z) * a0.y;
    z = bf_lo(lA.y) + bf_lo(rA.y); vA += (z > 0.f ? z : 0.2f * z) * a0.z;
    z = bf_hi(lA.y) + bf_hi(rA.y); vA += (z > 0.f ? z : 0.2f * z) * a0.w;
    z = bf_lo(lA.z) + bf_lo(rA.z); vA += (z > 0.f ? z : 0.2f * z) * a1.x;
    z = bf_hi(lA.z) + bf_hi(rA.z); vA += (z > 0.f ? z : 0.2f * z) * a1.y;
    z = bf_lo(lA.w) + bf_lo(rA.w); vA += (z > 0.f ? z : 0.2f * z) * a1.z;
    z = bf_hi(lA.w) + bf_hi(rA.w); vA += (z > 0.f ? z : 0.2f * z) * a1.w;
    z = bf_lo(lB.x) + bf_lo(rB.x); vB += (z > 0.f ? z : 0.2f * z) * a0.x;
    z = bf_hi(lB.x) + bf_hi(rB.x); vB += (z > 0.f ? z : 0.2f * z) * a0.y;
    z = bf_lo(lB.y) + bf_lo(rB.y); vB += (z > 0.f ? z : 0.2f * z) * a0.z;
    z = bf_hi(lB.y) + bf_hi(rB.y); vB += (z > 0.f ? z : 0.2f * z) * a0.w;
    z = bf_lo(lB.z) + bf_lo(rB.z); vB += (z > 0.f ? z : 0.2f * z) * a1.x;
    z = bf_hi(lB.z) + bf_hi(rB.z); vB += (z > 0.f ? z : 0.2f * z) * a1.y;
    z = bf_lo(lB.w) + bf_lo(rB.w); vB += (z > 0.f ? z : 0.2f * z) * a1.z;
    z = bf_hi(lB.w) + bf_hi(rB.w); vB += (z > 0.f ? z : 0.2f * z) * a1.w;
#pragma unroll
    for (int o = 8; o > 0; o >>= 1) vA += __shfl_xor(vA, o, 64);
#pragma unroll
    for (int o = 8; o > 0; o >>= 1) vB += __shfl_xor(vB, o, 64);
    if (q == 0) {
      if (okA) { e_sc[eA] = vA; atomicMax(&m_enc[dA], encf(vA)); }
      if (okB) { e_sc[eB] = vB; atomicMax(&m_enc[dB], encf(vB)); }
    }
  }
}

// ---------- edge pass 2: denominator ----------

__global__ __launch_bounds__(256) void seg_expsum(
    const float* __restrict__ e_sc, const int* __restrict__ dst,
    const unsigned int* __restrict__ m_enc, float* __restrict__ s_sum, int ne) {
  int i = blockIdx.x * 256 + threadIdx.x;
  if (i < ne) {
    int d_ = dst[i];
    float ex = expf(e_sc[i] - decf(m_enc[d_]));
    atomicAdd(&s_sum[d_], ex);
  }
}

// ---------- edge pass 3a: per-source scalar coefficients ----------

__global__ __launch_bounds__(256) void edge_coef(
    const float* __restrict__ e_sc, const int* __restrict__ src,
    const int* __restrict__ dst, const unsigned int* __restrict__ m_enc,
    const float* __restrict__ s_sum, float* __restrict__ coef, int ne) {
  int i = blockIdx.x * 256 + threadIdx.x;
  if (i < ne) {
    int d_ = dst[i];
    float w = expf(e_sc[i] - decf(m_enc[d_])) / s_sum[d_];
    atomicAdd(&coef[src[i]], w);
  }
}

// ---------- edge pass 3b: g_acc[d] = sum_s coef[s] * xlh[s][d] (bf16 rows) ------

__global__ __launch_bounds__(256) void weighted_sum(
    const unsigned short* __restrict__ xlh, const float* __restrict__ coef,
    float* __restrict__ g_acc, int ns) {
  __shared__ float red[4][D];
  int lane = threadIdx.x & 63;
  int wv = threadIdx.x >> 6;
  int wid = blockIdx.x * 4 + wv;
  int nw = gridDim.x * 4;
  float ax = 0.f, ay = 0.f;
  for (int s = wid; s < ns; s += nw) {
    float w = coef[s];
    unsigned int u = ((const unsigned int*)(xlh + (long long)s * D))[lane];
    ax += w * bf_lo(u);
    ay += w * bf_hi(u);
  }
  red[wv][2 * lane] = ax;
  red[wv][2 * lane + 1] = ay;
  __syncthreads();
  if (threadIdx.x < D) {
    float t = red[0][threadIdx.x] + red[1][threadIdx.x] + red[2][threadIdx.x] +
              red[3][threadIdx.x];
    atomicAdd(&g_acc[threadIdx.x], t);
  }
}

// ---------- per-step: redundant gates/cell/hidden + logits/gumbel ----------
// Every block recomputes the (tiny) LSTM state for step t from amax[t-1];
// Wih/Whh (512 KB) are L2-resident per XCD, so the redundancy is cheap.
// logits double-buffered: step t writes slot t&1, reads prev from (t+1)&1.

__global__ __launch_bounds__(256) void chain_step(
    const float* __restrict__ Wih, const float* __restrict__ Whh,
    const float* __restrict__ bih, const float* __restrict__ bhh,
    const float* __restrict__ emb, const float* __restrict__ conv_bias,
    const float* __restrict__ g_acc, const float* __restrict__ W1,
    const float* __restrict__ b1, const float* __restrict__ W2,
    const float* __restrict__ b2, float* __restrict__ st_h,
    float* __restrict__ st_c, float* __restrict__ logits,
    unsigned long long* __restrict__ amax, float* __restrict__ sumexp,
    float* __restrict__ out, int nm, float nmf, int t) {
  __shared__ float vin[D], hprev[D], hid[D];
  __shared__ float gts[4 * D];
  __shared__ float rs[256];
  int tid = threadIdx.x;
  int bid = blockIdx.x;

  int a = 0;
  if (t > 0) {
    unsigned long long p = amax[t - 1];
    a = (int)(0xFFFFFFFFu - (unsigned int)(p & 0xFFFFFFFFull));
    a = a < 0 ? 0 : (a >= nm ? nm - 1 : a);
  }
  if (tid < D) {
    vin[tid] = (t == 0) ? (g_acc[tid] / nmf + conv_bias[tid])
                        : emb[(long long)a * D + tid];
    hprev[tid] = (t == 0) ? 0.f : st_h[(t & 1) * D + tid];
  }
  if (t > 0 && bid == 0 && tid == 255) {
    const float* logits_prev = logits + ((t + 1) & 1) * nm;
    out[t - 1] = (float)a;
    out[8 + t - 1] = logits_prev[a] - logf(sumexp[t - 1]);
  }
  __syncthreads();

  // gates (all threads; 2 rows each)
  for (int r = tid; r < 4 * D; r += 256) {
    const float4* wi = (const float4*)(Wih + (long long)r * D);
    const float4* wh = (const float4*)(Whh + (long long)r * D);
    float s0 = 0.f, s1 = 0.f, s2 = 0.f, s3 = 0.f;
#pragma unroll 8
    for (int k = 0; k < 32; ++k) {
      float4 wa = wi[k], wb = wh[k];
      s0 += wa.x * vin[4 * k] + wb.x * hprev[4 * k];
      s1 += wa.y * vin[4 * k + 1] + wb.y * hprev[4 * k + 1];
      s2 += wa.z * vin[4 * k + 2] + wb.z * hprev[4 * k + 2];
      s3 += wa.w * vin[4 * k + 3] + wb.w * hprev[4 * k + 3];
    }
    gts[r] = ((s0 + s1) + (s2 + s3)) + bih[r] + bhh[r];
  }
  __syncthreads();

  // cell update
  if (tid < D) {
    float cprev = (t == 0) ? 0.f : st_c[(t & 1) * D + tid];
    float i_ = 1.f / (1.f + expf(-gts[tid]));
    float f_ = 1.f / (1.f + expf(-gts[D + tid]));
    float g_ = tanhf(gts[2 * D + tid]);
    float o_ = 1.f / (1.f + expf(-gts[3 * D + tid]));
    float cn = f_ * cprev + i_ * g_;
    float hn = o_ * tanhf(cn);
    hprev[tid] = hn;  // reuse as h_new
    if (bid == 0) {
      st_c[((t + 1) & 1) * D + tid] = cn;
      st_h[((t + 1) & 1) * D + tid] = hn;
    }
  }
  __syncthreads();

  // predictor hidden
  if (tid < D) {
    const float4* w = (const float4*)(W1 + tid * D);
    float s0 = 0.f, s1 = 0.f, s2 = 0.f, s3 = 0.f;
#pragma unroll 8
    for (int k = 0; k < 32; ++k) {
      float4 ww = w[k];
      s0 += ww.x * hprev[4 * k];
      s1 += ww.y * hprev[4 * k + 1];
      s2 += ww.z * hprev[4 * k + 2];
      s3 += ww.w * hprev[4 * k + 3];
    }
    hid[tid] = fmaxf(((s0 + s1) + (s2 + s3)) + b1[tid], 0.f);
  }
  __syncthreads();

  // logits + gumbel + argmax + sumexp
  int j = bid * 256 + tid;
  float ex = 0.f;
  float* logits_cur = logits + (t & 1) * nm;
  if (j < nm) {
    const float4* w = (const float4*)(W2 + (long long)j * D);
    float s0 = 0.f, s1 = 0.f, s2 = 0.f, s3 = 0.f;
#pragma unroll 8
    for (int k = 0; k < 32; ++k) {
      float4 ww = w[k];
      s0 += ww.x * hid[4 * k];
      s1 += ww.y * hid[4 * k + 1];
      s2 += ww.z * hid[4 * k + 2];
      s3 += ww.w * hid[4 * k + 3];
    }
    float lv = ((s0 + s1) + (s2 + s3)) + b2[j];
    logits_cur[j] = lv;
    ex = expf(lv);
    unsigned int k0 = 0u, k1 = (unsigned int)t;
    tf2x32(0u, 42u, k0, k1);  // key_t = cipher((0,42),(0,t))
    unsigned int x0 = 0u, x1 = (unsigned int)j;
    tf2x32(k0, k1, x0, x1);
    unsigned int bits = x0 ^ x1;
    float f = __uint_as_float((bits >> 9) | 0x3f800000u) - 1.0f;
    const float tiny = 1.1754943508222875e-38f;
    float u = fmaxf(tiny, f * (1.0f - tiny) + tiny);
    float gmb = -logf(-logf(u));
    float pert = lv + gmb;
    unsigned long long pk = ((unsigned long long)encf(pert) << 32) |
                            (unsigned long long)(0xFFFFFFFFu - (unsigned int)j);
    atomicMax(&amax[t], pk);
  }
  rs[tid] = ex;
  __syncthreads();
  for (int s = 128; s > 0; s >>= 1) {
    if (tid < s) rs[tid] += rs[tid + s];
    __syncthreads();
  }
  if (tid == 0) atomicAdd(&sumexp[t], rs[0]);
}

// ---------- final outputs ----------

__global__ __launch_bounds__(128) void final_out(
    const float* __restrict__ st_h, const float* __restrict__ st_c,
    const float* __restrict__ logits, const unsigned long long* __restrict__ amax,
    const float* __restrict__ sumexp, float* __restrict__ out, int nm) {
  int tid = threadIdx.x;
  if (tid == 0) {
    unsigned long long p = amax[7];
    int a = (int)(0xFFFFFFFFu - (unsigned int)(p & 0xFFFFFFFFull));
    a = a < 0 ? 0 : (a >= nm ? nm - 1 : a);
    out[7] = (float)a;
    out[15] = logits[a] - logf(sumexp[7]);  // logits slot 7&1=1 passed in
  }
  out[16 + tid] = st_h[tid];   // slot 0 = (7+1)&1
  out[144 + tid] = st_c[tid];
}

// ---------- launch ----------

extern "C" void kernel_launch(void* const* d_in, const int* in_sizes, int n_in,
                              void* d_out, int out_size, void* d_ws, size_t ws_size,
                              hipStream_t stream) {
  const float* state_features = (const float*)d_in[0];
  const float* model_features = (const float*)d_in[1];
  const int* edge_index = (const int*)d_in[2];
  const float* W_l = (const float*)d_in[3];
  const float* W_r = (const float*)d_in[4];
  const float* att = (const float*)d_in[5];
  const float* conv_bias = (const float*)d_in[6];
  const float* Wih = (const float*)d_in[7];
  const float* Whh = (const float*)d_in[8];
  const float* bih = (const float*)d_in[9];
  const float* bhh = (const float*)d_in[10];
  const float* W1 = (const float*)d_in[11];
  const float* b1 = (const float*)d_in[12];
  const float* W2 = (const float*)d_in[13];
  const float* b2 = (const float*)d_in[14];
  const float* emb = (const float*)d_in[15];
  float* out = (float*)d_out;

  int NS = in_sizes[0] / D;
  int NM = in_sizes[1] / D;
  int E = in_sizes[2] / 2;

  char* ws = (char*)d_ws;
  size_t off = 0;
  auto alloc = [&](size_t bytes) -> void* {
    void* p = ws + off;
    off = (off + bytes + 255) & ~(size_t)255;
    return p;
  };
  unsigned short* xlh = (unsigned short*)alloc((size_t)NS * D * 2);
  unsigned short* xrh = (unsigned short*)alloc((size_t)NM * D * 2);
  float* e_sc = (float*)alloc((size_t)E * 4);
  int* src32 = (int*)alloc((size_t)E * 4);
  int* dst32 = (int*)alloc((size_t)E * 4);
  unsigned int* m_enc = (unsigned int*)alloc((size_t)NM * 4);
  float* s_sum = (float*)alloc((size_t)NM * 4);
  float* coef = (float*)alloc((size_t)NS * 4);
  float* logits = (float*)alloc((size_t)2 * NM * 4);  // double-buffered
  float* g_acc = (float*)alloc(D * 4);
  float* st_h = (float*)alloc(2 * D * 4);
  float* st_c = (float*)alloc(2 * D * 4);
  float* st_sumexp = (float*)alloc(8 * 4);
  unsigned long long* st_amax = (unsigned long long*)alloc(8 * 8);

  // node 1: prologue + both GEMMs
  int slabs = (NS + 127) / 128 + (NM + 127) / 128;
  gemm_pro<<<slabs, 256, 0, stream>>>(state_features, model_features, W_l, W_r,
                                      xlh, xrh, edge_index, src32, dst32, m_enc,
                                      s_sum, coef, g_acc, st_amax, st_sumexp, E,
                                      NS, NM);

  // nodes 2-5: edge passes
  edge_scores<<<2048, 256, 0, stream>>>(xlh, xrh, src32, dst32, att, e_sc,
                                        m_enc, E);
  seg_expsum<<<(E + 255) / 256, 256, 0, stream>>>(e_sc, dst32, m_enc, s_sum, E);
  edge_coef<<<(E + 255) / 256, 256, 0, stream>>>(e_sc, src32, dst32, m_enc,
                                                 s_sum, coef, E);
  weighted_sum<<<1024, 256, 0, stream>>>(xlh, coef, g_acc, NS);

  // nodes 6-13: 8 chain steps
  float nmf = (float)NM;
  int NB = (NM + 255) / 256;
  for (int t = 0; t < 8; ++t) {
    chain_step<<<NB, 256, 0, stream>>>(Wih, Whh, bih, bhh, emb, conv_bias,
                                       g_acc, W1, b1, W2, b2, st_h, st_c,
                                       logits, st_amax, st_sumexp, out, NM, nmf,
                                       t);
  }

  // node 14: final h/c + last action
  final_out<<<1, 128, 0, stream>>>(st_h, st_c, logits + NM, st_amax, st_sumexp,
                                   out, NM);
}

// Round 9
// 650.582 us; speedup vs baseline: 2.2078x; 1.0390x over previous
//
#include <hip/hip_runtime.h>

#define D 128
#define WTS2 160  // swizzled LDS row stride (words) for gemm staging

// ---------- helpers ----------

__device__ __forceinline__ unsigned int encf(float f) {
  unsigned int u = __float_as_uint(f);
  return (u & 0x80000000u) ? ~u : (u | 0x80000000u);
}
__device__ __forceinline__ float decf(unsigned int e) {
  return __uint_as_float((e & 0x80000000u) ? (e & 0x7FFFFFFFu) : ~e);
}
__device__ __forceinline__ unsigned short f2bf(float f) {
  unsigned int u = __float_as_uint(f);
  u += 0x7FFFu + ((u >> 16) & 1u);  // rne
  return (unsigned short)(u >> 16);
}
__device__ __forceinline__ float bf_lo(unsigned int u) {
  return __uint_as_float(u << 16);
}
__device__ __forceinline__ float bf_hi(unsigned int u) {
  return __uint_as_float(u & 0xFFFF0000u);
}

// JAX threefry2x32 (20 rounds), exact.
__device__ __forceinline__ void tf2x32(unsigned int k0, unsigned int k1,
                                       unsigned int& x0, unsigned int& x1) {
  unsigned int ks[3] = {k0, k1, k0 ^ k1 ^ 0x1BD11BDAu};
  x0 += ks[0]; x1 += ks[1];
  const unsigned int rotA[4] = {13u, 15u, 26u, 6u};
  const unsigned int rotB[4] = {17u, 29u, 16u, 24u};
#pragma unroll
  for (int g = 0; g < 5; ++g) {
    const unsigned int* rot = (g & 1) ? rotB : rotA;
#pragma unroll
    for (int i = 0; i < 4; ++i) {
      x0 += x1;
      x1 = (x1 << rot[i]) | (x1 >> (32u - rot[i]));
      x1 ^= x0;
    }
    x0 += ks[(g + 1) % 3];
    x1 += ks[(g + 2) % 3] + (unsigned int)(g + 1);
  }
}

// ---------- node 1: prologue (zero + edge-normalize) + both GEMMs ----------
// LDS swizzle: WT word index = k*WTS2 + c + 4*((k>>2)&7). Write banks =
// (c + 4*(j&7)) & 31 -> 32 banks, 2 lanes each (free). Reads stay float4-
// contiguous (uniform per-k shift) -> broadcast, free.

__global__ __launch_bounds__(256) void gemm_pro(
    const float* __restrict__ Xs, const float* __restrict__ Xm,
    const float* __restrict__ Wl, const float* __restrict__ Wr,
    unsigned short* __restrict__ Yxlh, unsigned short* __restrict__ Yxrh,
    const int* __restrict__ ei, int* __restrict__ src32,
    int* __restrict__ dst32, unsigned int* __restrict__ m_enc,
    float* __restrict__ s_sum, float* __restrict__ coef,
    float* __restrict__ g_acc, unsigned int* __restrict__ done,
    float* __restrict__ sumexp, int ne, int ns, int nm) {
  int tid = threadIdx.x;
  int gid = blockIdx.x * 256 + tid;
  int gstride = gridDim.x * 256;

  // ---- prologue: zero accumulators ----
  for (int i = gid; i < nm; i += gstride) { m_enc[i] = 0u; s_sum[i] = 0.f; }
  for (int i = gid; i < ns; i += gstride) coef[i] = 0.f;
  if (gid < D) g_acc[gid] = 0.f;
  if (gid < 8) { done[gid] = 0u; sumexp[gid] = 0.f; }
  // ---- prologue: edge index normalization (int32 vs int64 runtime detect) ----
  __shared__ int is64;
  if (tid == 0) {
    int any = 0;
    for (int i = 1; i < 256; i += 2) any |= ei[i];
    is64 = (any == 0);
  }
  __syncthreads();
  int flag = is64;
  for (int i = gid; i < ne; i += gstride) {
    int s = flag ? ei[2 * i] : ei[i];
    int d = flag ? ei[2 * ne + 2 * i] : ei[ne + i];
    s = s < 0 ? 0 : (s >= ns ? ns - 1 : s);
    d = d < 0 ? 0 : (d >= nm ? nm - 1 : d);
    src32[i] = s;
    dst32[i] = d;
  }

  // ---- both GEMMs via slab loop ----
  __shared__ float WT[64 * WTS2];
  int q = tid & 15;
  int rg = tid >> 4;
  int slabs_s = (ns + 127) >> 7;
  int slabs_m = (nm + 127) >> 7;

  for (int sl = blockIdx.x; sl < slabs_s + slabs_m; sl += gridDim.x) {
    const float* X; const float* W; unsigned short* Yh; int N;
    long long r0;
    if (sl < slabs_s) {
      X = Xs; W = Wl; Yh = Yxlh; N = ns;
      r0 = (long long)sl * 128;
    } else {
      X = Xm; W = Wr; Yh = Yxrh; N = nm;
      r0 = (long long)(sl - slabs_s) * 128;
    }

    float acc[8][8];
#pragma unroll
    for (int r = 0; r < 8; ++r)
#pragma unroll
      for (int c = 0; c < 8; ++c) acc[r][c] = 0.f;

    long long rbase = r0 + (long long)rg * 8;
    if (rbase > (long long)N - 8) rbase = (long long)N - 8;

#pragma unroll
    for (int phase = 0; phase < 2; ++phase) {
      const int kbase = phase * 64;
      __syncthreads();
      // stage W[c][kbase+4j..+3] -> swizzled WT
      for (int i = tid; i < 2048; i += 256) {
        int c = i >> 4;
        int j = i & 15;
        float4 w4 = *(const float4*)(W + c * D + kbase + 4 * j);
        int sh = 4 * (j & 7);  // (k>>2)&7 == j&7 for k=4j+idx
        WT[(4 * j + 0) * WTS2 + c + sh] = w4.x;
        WT[(4 * j + 1) * WTS2 + c + sh] = w4.y;
        WT[(4 * j + 2) * WTS2 + c + sh] = w4.z;
        WT[(4 * j + 3) * WTS2 + c + sh] = w4.w;
      }
      __syncthreads();

      for (int k4 = 0; k4 < 64; k4 += 4) {
        float4 xr_[8];
#pragma unroll
        for (int r = 0; r < 8; ++r)
          xr_[r] = *(const float4*)(X + (rbase + r) * D + kbase + k4);
#pragma unroll
        for (int kk = 0; kk < 4; ++kk) {
          int k = k4 + kk;
          int sh = 4 * ((k >> 2) & 7);
          float4 wa = *(const float4*)(WT + k * WTS2 + 4 * q + sh);
          float4 wb = *(const float4*)(WT + k * WTS2 + 64 + 4 * q + sh);
#pragma unroll
          for (int r = 0; r < 8; ++r) {
            float xv = (&xr_[r].x)[kk];
            acc[r][0] += xv * wa.x; acc[r][1] += xv * wa.y;
            acc[r][2] += xv * wa.z; acc[r][3] += xv * wa.w;
            acc[r][4] += xv * wb.x; acc[r][5] += xv * wb.y;
            acc[r][6] += xv * wb.z; acc[r][7] += xv * wb.w;
          }
        }
      }
    }

#pragma unroll
    for (int r = 0; r < 8; ++r) {
      unsigned short* hp = Yh + (rbase + r) * D;
      uint2 pa, pb;
      pa.x = (unsigned int)f2bf(acc[r][0]) | ((unsigned int)f2bf(acc[r][1]) << 16);
      pa.y = (unsigned int)f2bf(acc[r][2]) | ((unsigned int)f2bf(acc[r][3]) << 16);
      pb.x = (unsigned int)f2bf(acc[r][4]) | ((unsigned int)f2bf(acc[r][5]) << 16);
      pb.y = (unsigned int)f2bf(acc[r][6]) | ((unsigned int)f2bf(acc[r][7]) << 16);
      *(uint2*)(hp + 4 * q) = pa;
      *(uint2*)(hp + 64 + 4 * q) = pb;
    }
  }
}

// ---------- edge pass 1: scores + segment max (bf16 rows, quarter-wave/edge x2) --

__global__ __launch_bounds__(256) void edge_scores(
    const unsigned short* __restrict__ xlh, const unsigned short* __restrict__ xrh,
    const int* __restrict__ src, const int* __restrict__ dst,
    const float* __restrict__ att, float* __restrict__ e_sc,
    unsigned int* __restrict__ m_enc, int ne) {
  int tid = threadIdx.x;
  int lane = tid & 63;
  int q = lane & 15;
  int sub = lane >> 4;
  int wid = (blockIdx.x * 256 + tid) >> 6;
  int nw = (gridDim.x * 256) >> 6;
  float4 a0 = ((const float4*)att)[2 * q];
  float4 a1 = ((const float4*)att)[2 * q + 1];
  for (int e0 = wid * 8; e0 < ne; e0 += nw * 8) {
    int eA = e0 + sub, eB = e0 + 4 + sub;
    int okA = eA < ne, okB = eB < ne;
    int sA = okA ? src[eA] : 0, dA = okA ? dst[eA] : 0;
    int sB = okB ? src[eB] : 0, dB = okB ? dst[eB] : 0;
    uint4 lA = *(const uint4*)(xlh + (long long)sA * D + q * 8);
    uint4 rA = *(const uint4*)(xrh + (long long)dA * D + q * 8);
    uint4 lB = *(const uint4*)(xlh + (long long)sB * D + q * 8);
    uint4 rB = *(const uint4*)(xrh + (long long)dB * D + q * 8);
    float z, vA = 0.f, vB = 0.f;
    z = bf_lo(lA.x) + bf_lo(rA.x); vA += (z > 0.f ? z : 0.2f * z) * a0.x;
    z = bf_hi(lA.x) + bf_hi(rA.x); vA += (z > 0.f ? z : 0.2f * z) * a0.y;
    z = bf_lo(lA.y) + bf_lo(rA.y); vA += (z > 0.f ? z : 0.2f * z) * a0.z;
    z = bf_hi(lA.y) + bf_hi(rA.y); vA += (z > 0.f ? z : 0.2f * z) * a0.w;
    z = bf_lo(lA.z) + bf_lo(rA.z); vA += (z > 0.f ? z : 0.2f * z) * a1.x;
    z = bf_hi(lA.z) + bf_hi(rA.z); vA += (z > 0.f ? z : 0.2f * z) * a1.y;
    z = bf_lo(lA.w) + bf_lo(rA.w); vA += (z > 0.f ? z : 0.2f * z) * a1.z;
    z = bf_hi(lA.w) + bf_hi(rA.w); vA += (z > 0.f ? z : 0.2f * z) * a1.w;
    z = bf_lo(lB.x) + bf_lo(rB.x); vB += (z > 0.f ? z : 0.2f * z) * a0.x;
    z = bf_hi(lB.x) + bf_hi(rB.x); vB += (z > 0.f ? z : 0.2f * z) * a0.y;
    z = bf_lo(lB.y) + bf_lo(rB.y); vB += (z > 0.f ? z : 0.2f * z) * a0.z;
    z = bf_hi(lB.y) + bf_hi(rB.y); vB += (z > 0.f ? z : 0.2f * z) * a0.w;
    z = bf_lo(lB.z) + bf_lo(rB.z); vB += (z > 0.f ? z : 0.2f * z) * a1.x;
    z = bf_hi(lB.z) + bf_hi(rB.z); vB += (z > 0.f ? z : 0.2f * z) * a1.y;
    z = bf_lo(lB.w) + bf_lo(rB.w); vB += (z > 0.f ? z : 0.2f * z) * a1.z;
    z = bf_hi(lB.w) + bf_hi(rB.w); vB += (z > 0.f ? z : 0.2f * z) * a1.w;
#pragma unroll
    for (int o = 8; o > 0; o >>= 1) vA += __shfl_xor(vA, o, 64);
#pragma unroll
    for (int o = 8; o > 0; o >>= 1) vB += __shfl_xor(vB, o, 64);
    if (q == 0) {
      if (okA) { e_sc[eA] = vA; atomicMax(&m_enc[dA], encf(vA)); }
      if (okB) { e_sc[eB] = vB; atomicMax(&m_enc[dB], encf(vB)); }
    }
  }
}

// ---------- edge pass 2: denominator ----------

__global__ __launch_bounds__(256) void seg_expsum(
    const float* __restrict__ e_sc, const int* __restrict__ dst,
    const unsigned int* __restrict__ m_enc, float* __restrict__ s_sum, int ne) {
  int i = blockIdx.x * 256 + threadIdx.x;
  if (i < ne) {
    int d_ = dst[i];
    float ex = expf(e_sc[i] - decf(m_enc[d_]));
    atomicAdd(&s_sum[d_], ex);
  }
}

// ---------- edge pass 3a: per-source scalar coefficients ----------

__global__ __launch_bounds__(256) void edge_coef(
    const float* __restrict__ e_sc, const int* __restrict__ src,
    const int* __restrict__ dst, const unsigned int* __restrict__ m_enc,
    const float* __restrict__ s_sum, float* __restrict__ coef, int ne) {
  int i = blockIdx.x * 256 + threadIdx.x;
  if (i < ne) {
    int d_ = dst[i];
    float w = expf(e_sc[i] - decf(m_enc[d_])) / s_sum[d_];
    atomicAdd(&coef[src[i]], w);
  }
}

// ---------- edge pass 3b: g_acc[d] = sum_s coef[s] * xlh[s][d] (bf16 rows) ------

__global__ __launch_bounds__(256) void weighted_sum(
    const unsigned short* __restrict__ xlh, const float* __restrict__ coef,
    float* __restrict__ g_acc, int ns) {
  __shared__ float red[4][D];
  int lane = threadIdx.x & 63;
  int wv = threadIdx.x >> 6;
  int wid = blockIdx.x * 4 + wv;
  int nw = gridDim.x * 4;
  float ax = 0.f, ay = 0.f;
  for (int s = wid; s < ns; s += nw) {
    float w = coef[s];
    unsigned int u = ((const unsigned int*)(xlh + (long long)s * D))[lane];
    ax += w * bf_lo(u);
    ay += w * bf_hi(u);
  }
  red[wv][2 * lane] = ax;
  red[wv][2 * lane + 1] = ay;
  __syncthreads();
  if (threadIdx.x < D) {
    float t = red[0][threadIdx.x] + red[1][threadIdx.x] + red[2][threadIdx.x] +
              red[3][threadIdx.x];
    atomicAdd(&g_acc[threadIdx.x], t);
  }
}

// ---------- init: t=0 state (gates from h0=0, cell, predictor hidden) ----------

__global__ __launch_bounds__(256) void init_chain(
    const float* __restrict__ g_acc, const float* __restrict__ conv_bias,
    const float* __restrict__ Wih, const float* __restrict__ bih,
    const float* __restrict__ bhh, const float* __restrict__ W1,
    const float* __restrict__ b1, float* __restrict__ st_h,
    float* __restrict__ st_c, float* __restrict__ st_hidden, float nm) {
  __shared__ float vin[D], hh[D], gts[4 * D];
  int tid = threadIdx.x;
  if (tid < D) vin[tid] = g_acc[tid] / nm + conv_bias[tid];
  __syncthreads();
  for (int r = tid; r < 4 * D; r += 256) {
    const float4* wi = (const float4*)(Wih + (long long)r * D);
    float s0 = 0.f, s1 = 0.f, s2 = 0.f, s3 = 0.f;
#pragma unroll 8
    for (int k = 0; k < 32; ++k) {
      float4 w = wi[k];
      s0 += w.x * vin[4 * k];
      s1 += w.y * vin[4 * k + 1];
      s2 += w.z * vin[4 * k + 2];
      s3 += w.w * vin[4 * k + 3];
    }
    gts[r] = ((s0 + s1) + (s2 + s3)) + bih[r] + bhh[r];  // h0 = 0
  }
  __syncthreads();
  if (tid < D) {
    float i_ = 1.f / (1.f + expf(-gts[tid]));
    float g_ = tanhf(gts[2 * D + tid]);
    float o_ = 1.f / (1.f + expf(-gts[3 * D + tid]));
    float cn = i_ * g_;  // f*c0 = 0
    float hn = o_ * tanhf(cn);
    st_c[tid] = cn;
    st_h[tid] = hn;
    hh[tid] = hn;
  }
  __syncthreads();
  if (tid < D) {
    const float4* w = (const float4*)(W1 + tid * D);
    float s0 = 0.f, s1 = 0.f, s2 = 0.f, s3 = 0.f;
#pragma unroll 8
    for (int k = 0; k < 32; ++k) {
      float4 ww = w[k];
      s0 += ww.x * hh[4 * k];
      s1 += ww.y * hh[4 * k + 1];
      s2 += ww.z * hh[4 * k + 2];
      s3 += ww.w * hh[4 * k + 3];
    }
    st_hidden[tid] = fmaxf(((s0 + s1) + (s2 + s3)) + b1[tid], 0.f);
  }
}

// ---------- per-step fused: logits+gumbel (196 blocks, 1/thread) + last-block
// tail (argmax -> out -> gates/cell/hidden for t+1) ----------

__global__ __launch_bounds__(256) void chain_step(
    const float* __restrict__ Wih, const float* __restrict__ Whh,
    const float* __restrict__ bih, const float* __restrict__ bhh,
    const float* __restrict__ emb, const float* __restrict__ W1,
    const float* __restrict__ b1, const float* __restrict__ W2,
    const float* __restrict__ b2, float* __restrict__ st_h,
    float* __restrict__ st_c, float* __restrict__ st_hidden,
    float* __restrict__ sumexp, unsigned int* __restrict__ done,
    unsigned int* __restrict__ cand_enc, int* __restrict__ cand_j,
    float* __restrict__ cand_lg, float* __restrict__ out, int nm, int t) {
  __shared__ float hid[D];
  __shared__ unsigned int s_enc[256];
  __shared__ int s_j[256];
  __shared__ float s_lg[256], s_ex[256];
  __shared__ int s_flag;
  __shared__ float vin2[D], hc[D], gts[4 * D];
  int tid = threadIdx.x;
  if (tid < D) hid[tid] = st_hidden[tid];
  __syncthreads();
  unsigned int k0 = 0u, k1 = (unsigned int)t;
  tf2x32(0u, 42u, k0, k1);  // key_t = cipher((0,42),(0,t))
  int j = blockIdx.x * 256 + tid;
  unsigned int bestE = 0u;
  int bestJ = 0x7FFFFFFF;
  float bestL = 0.f, ex = 0.f;
  if (j < nm) {
    const float4* w = (const float4*)(W2 + (long long)j * D);
    float s0 = 0.f, s1 = 0.f, s2 = 0.f, s3 = 0.f;
#pragma unroll 8
    for (int k = 0; k < 32; ++k) {
      float4 ww = w[k];
      s0 += ww.x * hid[4 * k];
      s1 += ww.y * hid[4 * k + 1];
      s2 += ww.z * hid[4 * k + 2];
      s3 += ww.w * hid[4 * k + 3];
    }
    float lv = ((s0 + s1) + (s2 + s3)) + b2[j];
    ex = expf(lv);
    unsigned int x0 = 0u, x1 = (unsigned int)j;
    tf2x32(k0, k1, x0, x1);
    unsigned int bits = x0 ^ x1;
    float f = __uint_as_float((bits >> 9) | 0x3f800000u) - 1.0f;
    const float tiny = 1.1754943508222875e-38f;
    float u = fmaxf(tiny, f * (1.0f - tiny) + tiny);
    float pert = lv + (-logf(-logf(u)));
    bestE = encf(pert);
    bestJ = j;
    bestL = lv;
  }
  s_enc[tid] = bestE; s_j[tid] = bestJ; s_lg[tid] = bestL; s_ex[tid] = ex;
  __syncthreads();
  for (int s = 128; s > 0; s >>= 1) {
    if (tid < s) {
      s_ex[tid] += s_ex[tid + s];
      unsigned int eo = s_enc[tid + s];
      if (eo > s_enc[tid] || (eo == s_enc[tid] && s_j[tid + s] < s_j[tid])) {
        s_enc[tid] = eo; s_j[tid] = s_j[tid + s]; s_lg[tid] = s_lg[tid + s];
      }
    }
    __syncthreads();
  }
  if (tid == 0) {
    cand_enc[blockIdx.x] = s_enc[0];
    cand_j[blockIdx.x] = s_j[0];
    cand_lg[blockIdx.x] = s_lg[0];
    atomicAdd(&sumexp[t], s_ex[0]);
    __threadfence();  // release cand writes + atomic before done++
    unsigned int old = atomicAdd(&done[t], 1u);
    s_flag = (old == gridDim.x - 1);
  }
  __syncthreads();
  if (!s_flag) return;
  __threadfence();  // acquire other blocks' writes
  // ---- tail (last-finishing block only) ----
  int nb = (int)gridDim.x;
  s_enc[tid] = (tid < nb) ? cand_enc[tid] : 0u;
  s_j[tid] = (tid < nb) ? cand_j[tid] : 0x7FFFFFFF;
  s_lg[tid] = (tid < nb) ? cand_lg[tid] : 0.f;
  __syncthreads();
  for (int s = 128; s > 0; s >>= 1) {
    if (tid < s) {
      unsigned int eo = s_enc[tid + s];
      if (eo > s_enc[tid] || (eo == s_enc[tid] && s_j[tid + s] < s_j[tid])) {
        s_enc[tid] = eo; s_j[tid] = s_j[tid + s]; s_lg[tid] = s_lg[tid + s];
      }
    }
    __syncthreads();
  }
  int a = s_j[0];
  float lga = s_lg[0];
  if (a < 0 || a >= nm) a = 0;
  if (tid == 0) {
    float se = atomicAdd(&sumexp[t], 0.0f);  // coherent read
    out[t] = (float)a;
    out[8 + t] = lga - logf(se);
  }
  if (t < 7) {
    if (tid < D) {
      vin2[tid] = emb[(long long)a * D + tid];
      hc[tid] = st_h[tid];
    }
    __syncthreads();
    for (int r = tid; r < 4 * D; r += 256) {
      const float4* wi = (const float4*)(Wih + (long long)r * D);
      const float4* wh = (const float4*)(Whh + (long long)r * D);
      float s0 = 0.f, s1 = 0.f, s2 = 0.f, s3 = 0.f;
#pragma unroll 8
      for (int k = 0; k < 32; ++k) {
        float4 wa = wi[k], wb = wh[k];
        s0 += wa.x * vin2[4 * k] + wb.x * hc[4 * k];
        s1 += wa.y * vin2[4 * k + 1] + wb.y * hc[4 * k + 1];
        s2 += wa.z * vin2[4 * k + 2] + wb.z * hc[4 * k + 2];
        s3 += wa.w * vin2[4 * k + 3] + wb.w * hc[4 * k + 3];
      }
      gts[r] = ((s0 + s1) + (s2 + s3)) + bih[r] + bhh[r];
    }
    __syncthreads();
    if (tid < D) {
      float i_ = 1.f / (1.f + expf(-gts[tid]));
      float f_ = 1.f / (1.f + expf(-gts[D + tid]));
      float g_ = tanhf(gts[2 * D + tid]);
      float o_ = 1.f / (1.f + expf(-gts[3 * D + tid]));
      float cn = f_ * st_c[tid] + i_ * g_;
      float hn = o_ * tanhf(cn);
      st_c[tid] = cn;
      st_h[tid] = hn;
      hc[tid] = hn;
    }
    __syncthreads();
    if (tid < D) {
      const float4* w = (const float4*)(W1 + tid * D);
      float s0 = 0.f, s1 = 0.f, s2 = 0.f, s3 = 0.f;
#pragma unroll 8
      for (int k = 0; k < 32; ++k) {
        float4 ww = w[k];
        s0 += ww.x * hc[4 * k];
        s1 += ww.y * hc[4 * k + 1];
        s2 += ww.z * hc[4 * k + 2];
        s3 += ww.w * hc[4 * k + 3];
      }
      st_hidden[tid] = fmaxf(((s0 + s1) + (s2 + s3)) + b1[tid], 0.f);
    }
  } else {
    if (tid < D) {
      out[16 + tid] = st_h[tid];
      out[144 + tid] = st_c[tid];
    }
  }
}

// ---------- launch ----------

extern "C" void kernel_launch(void* const* d_in, const int* in_sizes, int n_in,
                              void* d_out, int out_size, void* d_ws, size_t ws_size,
                              hipStream_t stream) {
  const float* state_features = (const float*)d_in[0];
  const float* model_features = (const float*)d_in[1];
  const int* edge_index = (const int*)d_in[2];
  const float* W_l = (const float*)d_in[3];
  const float* W_r = (const float*)d_in[4];
  const float* att = (const float*)d_in[5];
  const float* conv_bias = (const float*)d_in[6];
  const float* Wih = (const float*)d_in[7];
  const float* Whh = (const float*)d_in[8];
  const float* bih = (const float*)d_in[9];
  const float* bhh = (const float*)d_in[10];
  const float* W1 = (const float*)d_in[11];
  const float* b1 = (const float*)d_in[12];
  const float* W2 = (const float*)d_in[13];
  const float* b2 = (const float*)d_in[14];
  const float* emb = (const float*)d_in[15];
  float* out = (float*)d_out;

  int NS = in_sizes[0] / D;
  int NM = in_sizes[1] / D;
  int E = in_sizes[2] / 2;

  char* ws = (char*)d_ws;
  size_t off = 0;
  auto alloc = [&](size_t bytes) -> void* {
    void* p = ws + off;
    off = (off + bytes + 255) & ~(size_t)255;
    return p;
  };
  unsigned short* xlh = (unsigned short*)alloc((size_t)NS * D * 2);
  unsigned short* xrh = (unsigned short*)alloc((size_t)NM * D * 2);
  float* e_sc = (float*)alloc((size_t)E * 4);
  int* src32 = (int*)alloc((size_t)E * 4);
  int* dst32 = (int*)alloc((size_t)E * 4);
  unsigned int* m_enc = (unsigned int*)alloc((size_t)NM * 4);
  float* s_sum = (float*)alloc((size_t)NM * 4);
  float* coef = (float*)alloc((size_t)NS * 4);
  float* g_acc = (float*)alloc(D * 4);
  float* st_h = (float*)alloc(D * 4);
  float* st_c = (float*)alloc(D * 4);
  float* st_hidden = (float*)alloc(D * 4);
  float* st_sumexp = (float*)alloc(8 * 4);
  unsigned int* st_done = (unsigned int*)alloc(8 * 4);
  unsigned int* cand_enc = (unsigned int*)alloc(256 * 4);
  int* cand_j = (int*)alloc(256 * 4);
  float* cand_lg = (float*)alloc(256 * 4);

  // node 1: prologue + both GEMMs
  int slabs = (NS + 127) / 128 + (NM + 127) / 128;
  gemm_pro<<<slabs, 256, 0, stream>>>(state_features, model_features, W_l, W_r,
                                      xlh, xrh, edge_index, src32, dst32, m_enc,
                                      s_sum, coef, g_acc, st_done, st_sumexp, E,
                                      NS, NM);

  // nodes 2-5: edge passes
  edge_scores<<<2048, 256, 0, stream>>>(xlh, xrh, src32, dst32, att, e_sc,
                                        m_enc, E);
  seg_expsum<<<(E + 255) / 256, 256, 0, stream>>>(e_sc, dst32, m_enc, s_sum, E);
  edge_coef<<<(E + 255) / 256, 256, 0, stream>>>(e_sc, src32, dst32, m_enc,
                                                 s_sum, coef, E);
  weighted_sum<<<1024, 256, 0, stream>>>(xlh, coef, g_acc, NS);

  // node 6: t=0 LSTM state
  init_chain<<<1, 256, 0, stream>>>(g_acc, conv_bias, Wih, bih, bhh, W1, b1,
                                    st_h, st_c, st_hidden, (float)NM);

  // nodes 7-14: 8 fused chain steps
  int NB = (NM + 255) / 256;  // 196
  for (int t = 0; t < 8; ++t) {
    chain_step<<<NB, 256, 0, stream>>>(Wih, Whh, bih, bhh, emb, W1, b1, W2, b2,
                                       st_h, st_c, st_hidden, st_sumexp,
                                       st_done, cand_enc, cand_j, cand_lg, out,
                                       NM, t);
  }
}